// Round 5
// baseline (165.071 us; speedup 1.0000x reference)
//
#include <hip/hip_runtime.h>

#define N_NODES 100000
#define D 128
#define E_POS 262144
#define E_NEG 262144
#define E_TOT (E_POS + E_NEG)

typedef __attribute__((ext_vector_type(8))) short short8;  // 8 bf16 (4 VGPRs)
typedef __attribute__((ext_vector_type(4))) float f4;      // MFMA C/D frag

__device__ __forceinline__ unsigned f2bf_u(float f) {
    // round-to-nearest-even fp32 -> bf16 (inputs finite; no NaN path)
    unsigned u = __float_as_uint(f);
    return (u + 0x7fffu + ((u >> 16) & 1u)) >> 16;
}

__device__ __forceinline__ void glds16(const void* g, void* l) {
    // async 16-B global->LDS; LDS dest = l + lane*16 (wave-uniform l)
    __builtin_amdgcn_global_load_lds(
        (const __attribute__((address_space(1))) void*)g,
        (__attribute__((address_space(3))) void*)l, 16, 0, 0);
}

// ---------------------------------------------------------------------------
// Prep: pack W1 (fp32 [256,128]) into bf16 MFMA-B-fragment layout:
//   Wf[((h*4+ks)*4+q)*128 + c][j] = bf16( W1[h*128 + ks*32 + q*8 + j][c] )
// One aligned 16-B load per lane-frag. 64 KB total (L2-resident).
// ---------------------------------------------------------------------------
__global__ __launch_bounds__(256) void pack_w1(
    const float* __restrict__ W1, unsigned short* __restrict__ Wf)
{
    const int tid = blockIdx.x * 256 + threadIdx.x;   // 4096 groups
    if (tid >= 4096) return;
    const int h  = tid >> 11;
    const int ks = (tid >> 9) & 3;
    const int q  = (tid >> 7) & 3;
    const int c  = tid & 127;
    const int kb = h * 128 + ks * 32 + q * 8;
    const float* src = W1 + (size_t)kb * D + c;
    unsigned short tmp[8];
#pragma unroll
    for (int j = 0; j < 8; ++j) tmp[j] = (unsigned short)f2bf_u(src[(size_t)j * D]);
    *(uint4*)(Wf + (size_t)tid * 8) = *(const uint4*)tmp;
}

// ---------------------------------------------------------------------------
// Phase 1 (bf16 MFMA): UVb[n][j] (bf16) =
//   j<128 : sum_k x[n][k]*W1[k][j] + b1[j]      (U)
//   j>=128: sum_k x[n][k]*W1[128+k][j-128]      (V)
// 256 thr = 4 waves; 64 rows x 256 cols; wave w -> col slice w*64.
// x staged to LDS as bf16 (coalesced float4 loads); A-frags via ds_read_b128.
// B from packed Wf. Epilogue transposes C-frags through LDS.
// MFMA layouts (measured, m89/m91): A[m=lane&15][k=q*8+j],
// B[k=q*8+j][n=lane&15], C: col=lane&15, row=q*4+reg.
// ---------------------------------------------------------------------------
#define XRS 136   // staging row stride in shorts (272 B: 16-B aligned)
#define ERS 264   // epilogue row stride in shorts (528 B: 16-B aligned)

__global__ __launch_bounds__(256) void node_gemm_mfma(
    const float* __restrict__ x,            // [N, 128]
    const unsigned short* __restrict__ Wf,  // packed B frags
    const float* __restrict__ b1,           // [128]
    unsigned short* __restrict__ UVb)       // [N, 256] bf16
{
    __shared__ unsigned short Ls[64 * ERS]; // 33792 B; staging uses front 17 KB

    const int t    = threadIdx.x;
    const int w    = t >> 6;                // wave 0..3
    const int lane = t & 63;
    const int m16  = lane & 15;
    const int q    = lane >> 4;             // quad 0..3
    const int nb   = blockIdx.x * 64;
    const int h    = w >> 1;                // 0=U, 1=V
    const int cbase = (w & 1) * 64;

    // ---- stage x[64][128] -> bf16 LDS, coalesced ----
#pragma unroll
    for (int i = 0; i < 8; ++i) {
        const int s   = t + i * 256;        // slot of 4 floats, 0..2047
        const int row = s >> 5;
        const int c4  = s & 31;
        const int gr  = nb + row;
        float4 a = make_float4(0.f, 0.f, 0.f, 0.f);
        if (gr < N_NODES) a = *(const float4*)(x + (size_t)gr * D + c4 * 4);
        const unsigned p0 = (f2bf_u(a.y) << 16) | f2bf_u(a.x);
        const unsigned p1 = (f2bf_u(a.w) << 16) | f2bf_u(a.z);
        *(uint2*)&Ls[row * XRS + c4 * 4] = make_uint2(p0, p1);
    }
    __syncthreads();

    f4 acc[4][4];
#pragma unroll
    for (int i = 0; i < 4; ++i)
#pragma unroll
        for (int j = 0; j < 4; ++j) acc[i][j] = (f4){0.f, 0.f, 0.f, 0.f};

    int arow[4];
#pragma unroll
    for (int rt = 0; rt < 4; ++rt) arow[rt] = (rt * 16 + m16) * XRS;

#pragma unroll
    for (int ks = 0; ks < 4; ++ks) {
        const int kcol = ks * 32 + q * 8;
        short8 af[4], bfr[4];
#pragma unroll
        for (int rt = 0; rt < 4; ++rt)
            af[rt] = *(const short8*)&Ls[arow[rt] + kcol];
        const unsigned short* wfb =
            Wf + ((size_t)(((h * 4 + ks) * 4 + q) * 128 + cbase + m16)) * 8;
#pragma unroll
        for (int ct = 0; ct < 4; ++ct)
            bfr[ct] = *(const short8*)(wfb + (size_t)ct * 16 * 8);
#pragma unroll
        for (int rt = 0; rt < 4; ++rt)
#pragma unroll
            for (int ct = 0; ct < 4; ++ct)
                acc[rt][ct] = __builtin_amdgcn_mfma_f32_16x16x32_bf16(
                    af[rt], bfr[ct], acc[rt][ct], 0, 0, 0);
    }

    // b1 folds into the U half only (cols < 128 -> waves 0,1)
    float badd[4];
#pragma unroll
    for (int ct = 0; ct < 4; ++ct) {
        const int cg = w * 64 + ct * 16 + m16;
        badd[ct] = (h == 0) ? b1[cg] : 0.f;
    }

    __syncthreads();   // all A-frag reads done before we overwrite Ls

    // scatter C-frags (bf16) into LDS row-major
#pragma unroll
    for (int rt = 0; rt < 4; ++rt)
#pragma unroll
        for (int ct = 0; ct < 4; ++ct) {
            const int colg = w * 64 + ct * 16 + m16;
#pragma unroll
            for (int r = 0; r < 4; ++r) {
                const int row = rt * 16 + q * 4 + r;
                Ls[row * ERS + colg] =
                    (unsigned short)f2bf_u(acc[rt][ct][r] + badd[ct]);
            }
        }
    __syncthreads();

    // coalesced bf16 store: thread t -> row t>>2, 64-col chunk (t&3)
    const int r  = t >> 2;
    const int c0 = (t & 3) * 64;
    const int grow = nb + r;
    if (grow < N_NODES) {
        const uint4* s = (const uint4*)&Ls[r * ERS + c0];
        uint4* d = (uint4*)(UVb + (size_t)grow * 256 + c0);
#pragma unroll
        for (int i = 0; i < 8; ++i) d[i] = s[i];
    }
}

// ---------------------------------------------------------------------------
// Phase 2 (async-staged): out[e] = relu(U[src]+V[tar]) . W2 + b2.
// Block = 256 thr = 4 waves, 512 edges in 4 chunks of 128.
// Per chunk: waves 0,1 issue 16 global_load_lds dwordx4 each for the U rows,
// waves 2,3 for the V rows (one inst = 4 edge-halves = 1 KB LDS, 16 KB in
// flight per wave, zero data VGPRs). One barrier drains vmcnt; compute runs
// from LDS (ds_read_b128 + fp32 math + 4-step shuffle reduce).
// Edge-half rows are 256 B contiguous in LDS (glds constraint: base+lane*16,
// no padding allowed).
// ---------------------------------------------------------------------------
__global__ __launch_bounds__(256) void edge_score_glds(
    const unsigned short* __restrict__ UVb,
    const int* __restrict__ pos,            // [2, E_POS]
    const int* __restrict__ neg,            // [2, E_NEG]
    const float* __restrict__ W2,           // [128]
    const float* __restrict__ b2,           // [1]
    float* __restrict__ out)                // [E_TOT]
{
    __shared__ int sidx[512], tidx[512];
    __shared__ unsigned short Ub[128 * 128];  // 32 KB: 128 rows x 256 B
    __shared__ unsigned short Vb[128 * 128];  // 32 KB

    const int t   = threadIdx.x;
    const int bid = blockIdx.x;
    const int e0  = bid * 512;                       // global edge base
    const int* eidx = (bid < 512) ? pos : neg;       // E_POS = 512*512
    const int lb    = (bid < 512) ? e0 : e0 - E_POS;

    {   // stage indices coalesced
        const int2 sp = *(const int2*)(eidx + lb + 2 * t);
        const int2 tp = *(const int2*)(eidx + E_POS + lb + 2 * t);
        *(int2*)&sidx[2 * t] = sp;
        *(int2*)&tidx[2 * t] = tp;
    }
    __syncthreads();

    const int w    = t >> 6;
    const int lane = t & 63;
    const int g    = lane >> 4;             // 0..3: edge-within-inst
    const int l16  = lane & 15;
    const int cg   = t >> 4;                // compute group 0..15
    const int isV  = (w >= 2);
    const int slot0 = (w & 1) * 16;         // inst slot base within half
    const int* myidx = isV ? tidx : sidx;
    unsigned short* mybuf = isV ? Vb : Ub;
    const int hoff = isV ? 128 : 0;         // element offset into UV row

    const float4 wa = *(const float4*)(W2 + l16 * 8);
    const float4 wb = *(const float4*)(W2 + l16 * 8 + 4);
    const float bb = b2[0];

#define BF_LO(uv) __uint_as_float((uv) << 16)
#define BF_HI(uv) __uint_as_float((uv) & 0xffff0000u)

    for (int c = 0; c < 4; ++c) {
        const int ce = c * 128;

        // read all node ids for this chunk BEFORE first glds (no ds_read
        // lands between glds issues -> back-to-back async loads)
        int nid[16];
#pragma unroll
        for (int j = 0; j < 16; ++j)
            nid[j] = myidx[ce + (slot0 + j) * 4 + g];

#pragma unroll
        for (int j = 0; j < 16; ++j) {
            const int I = slot0 + j;        // 0..31 within this half
            const unsigned short* gp =
                UVb + (size_t)nid[j] * 256 + hoff + l16 * 8;
            unsigned short* lp = mybuf + (size_t)(I * 4) * 128;
            glds16(gp, lp);
        }
        __syncthreads();                    // drains vmcnt -> LDS filled

        // compute 8 edges per 16-lane group
#pragma unroll
        for (int k = 0; k < 8; ++k) {
            const int el = cg * 8 + k;
            const uint4 U = *(const uint4*)&Ub[el * 128 + l16 * 8];
            const uint4 V = *(const uint4*)&Vb[el * 128 + l16 * 8];
            float p = 0.f;
            p = fmaf(fmaxf(BF_LO(U.x) + BF_LO(V.x), 0.f), wa.x, p);
            p = fmaf(fmaxf(BF_HI(U.x) + BF_HI(V.x), 0.f), wa.y, p);
            p = fmaf(fmaxf(BF_LO(U.y) + BF_LO(V.y), 0.f), wa.z, p);
            p = fmaf(fmaxf(BF_HI(U.y) + BF_HI(V.y), 0.f), wa.w, p);
            p = fmaf(fmaxf(BF_LO(U.z) + BF_LO(V.z), 0.f), wb.x, p);
            p = fmaf(fmaxf(BF_HI(U.z) + BF_HI(V.z), 0.f), wb.y, p);
            p = fmaf(fmaxf(BF_LO(U.w) + BF_LO(V.w), 0.f), wb.z, p);
            p = fmaf(fmaxf(BF_HI(U.w) + BF_HI(V.w), 0.f), wb.w, p);
#pragma unroll
            for (int off = 8; off; off >>= 1) p += __shfl_xor(p, off, 64);
            if (l16 == 0) out[e0 + ce + el] = p + bb;
        }
        __syncthreads();                    // buffer reuse protection
    }
#undef BF_LO
#undef BF_HI
}

// ---------------------------------------------------------------------------
// Fallback (ws too small): one wave per edge, direct fp32 compute.
// ---------------------------------------------------------------------------
__global__ __launch_bounds__(64) void edge_naive(
    const float* __restrict__ x,
    const int* __restrict__ pos, const int* __restrict__ neg,
    const float* __restrict__ W1, const float* __restrict__ b1,
    const float* __restrict__ W2, const float* __restrict__ b2,
    float* __restrict__ out)
{
    const int lane = threadIdx.x;
    for (int e = blockIdx.x; e < E_TOT; e += gridDim.x) {
        int src, tar;
        if (e < E_POS) { src = pos[e]; tar = pos[E_POS + e]; }
        else { int e2 = e - E_POS; src = neg[e2]; tar = neg[E_NEG + e2]; }
        const float* xsrc = x + (size_t)src * D;
        const float* xtar = x + (size_t)tar * D;
        int j = lane * 2;
        float h0 = b1[j], h1 = b1[j + 1];
        for (int k = 0; k < D; ++k) {
            float a = xsrc[k], b = xtar[k];
            h0 = fmaf(a, W1[(size_t)k * D + j],       h0);
            h0 = fmaf(b, W1[(size_t)(k + D) * D + j], h0);
            h1 = fmaf(a, W1[(size_t)k * D + j + 1],       h1);
            h1 = fmaf(b, W1[(size_t)(k + D) * D + j + 1], h1);
        }
        float p = fmaf(fmaxf(h0, 0.f), W2[j], fmaxf(h1, 0.f) * W2[j + 1]);
#pragma unroll
        for (int off = 32; off > 0; off >>= 1) p += __shfl_xor(p, off, 64);
        if (lane == 0) out[e] = p + b2[0];
    }
}

extern "C" void kernel_launch(void* const* d_in, const int* in_sizes, int n_in,
                              void* d_out, int out_size, void* d_ws, size_t ws_size,
                              hipStream_t stream) {
    const float* x   = (const float*)d_in[0];
    const int*   pos = (const int*)d_in[1];
    const int*   neg = (const int*)d_in[2];
    const float* W1  = (const float*)d_in[3];
    const float* b1  = (const float*)d_in[4];
    const float* W2  = (const float*)d_in[5];
    const float* b2  = (const float*)d_in[6];
    float* out = (float*)d_out;

    const size_t uv_bytes = (size_t)N_NODES * 256 * sizeof(unsigned short);
    const size_t wf_bytes = 32768 * sizeof(unsigned short);
    if (ws_size >= uv_bytes + wf_bytes) {
        unsigned short* UVb = (unsigned short*)d_ws;
        unsigned short* Wfr = (unsigned short*)((char*)d_ws + uv_bytes);
        pack_w1<<<16, 256, 0, stream>>>(W1, Wfr);
        node_gemm_mfma<<<(N_NODES + 63) / 64, 256, 0, stream>>>(x, Wfr, b1, UVb);
        edge_score_glds<<<E_TOT / 512, 256, 0, stream>>>(UVb, pos, neg, W2, b2, out);
    } else {
        edge_naive<<<8192, 64, 0, stream>>>(x, pos, neg, W1, b1, W2, b2, out);
    }
}

// Round 6
// 155.855 us; speedup vs baseline: 1.0591x; 1.0591x over previous
//
#include <hip/hip_runtime.h>

#define N_NODES 100000
#define D 128
#define E_POS 262144
#define E_NEG 262144
#define E_TOT (E_POS + E_NEG)

typedef __attribute__((ext_vector_type(8))) short short8;  // 8 bf16 (4 VGPRs)
typedef __attribute__((ext_vector_type(4))) float f4;      // MFMA C/D frag

__device__ __forceinline__ unsigned f2bf_u(float f) {
    // round-to-nearest-even fp32 -> bf16 (inputs finite; no NaN path)
    unsigned u = __float_as_uint(f);
    return (u + 0x7fffu + ((u >> 16) & 1u)) >> 16;
}

// ---------------------------------------------------------------------------
// Prep: pack W1 (fp32 [256,128]) into bf16 MFMA fragment layout:
//   Wf[((h*4+ks)*4+q)*128 + c][j] = bf16( W1[h*128 + ks*32 + q*8 + j][c] )
// Serves as the A-operand (W1^T) in the swapped-orientation MFMA: the same
// bytes satisfy A[m=c][k=ks*32+q*8+j]. 64 KB total (L2-resident).
// ---------------------------------------------------------------------------
__global__ __launch_bounds__(256) void pack_w1(
    const float* __restrict__ W1, unsigned short* __restrict__ Wf)
{
    const int tid = blockIdx.x * 256 + threadIdx.x;   // 4096 groups
    if (tid >= 4096) return;
    const int h  = tid >> 11;
    const int ks = (tid >> 9) & 3;
    const int q  = (tid >> 7) & 3;
    const int c  = tid & 127;
    const int kb = h * 128 + ks * 32 + q * 8;
    const float* src = W1 + (size_t)kb * D + c;
    unsigned short tmp[8];
#pragma unroll
    for (int j = 0; j < 8; ++j) tmp[j] = (unsigned short)f2bf_u(src[(size_t)j * D]);
    *(uint4*)(Wf + (size_t)tid * 8) = *(const uint4*)tmp;
}

// ---------------------------------------------------------------------------
// Phase 1 (bf16 MFMA, swapped orientation): UVb[n][j] (bf16) =
//   j<128 : sum_k x[n][k]*W1[k][j] + b1[j]      (U)
//   j>=128: sum_k x[n][k]*W1[128+k][j-128]      (V)
// 512 thr = 8 waves; 64 nodes x 256 cols per block; wave w -> h=w>>2 half,
// 32-col slice (w&3)*32. D[m=j][n=node] = Wf(A) * x(B): per lane the C frag
// is 4 CONSECUTIVE j for one node -> epilogue uses ds_write_b64 (not b16).
// 8 waves on 33.8 KB LDS -> 4 blocks/CU = 32 waves/CU occupancy cap (100%).
// MFMA layouts (measured, m89/m91): A[m=lane&15][k=q*8+j],
// B[k=q*8+j][n=lane&15], C: col(n)=lane&15, row(m)=q*4+reg.
// ---------------------------------------------------------------------------
#define XRS 136   // staging row stride in shorts (272 B: 16-B aligned)
#define ERS 264   // epilogue row stride in shorts (528 B: 16-B aligned)

__global__ __launch_bounds__(512) void node_gemm_mfma(
    const float* __restrict__ x,            // [N, 128]
    const unsigned short* __restrict__ Wf,  // packed W1^T frags
    const float* __restrict__ b1,           // [128]
    unsigned short* __restrict__ UVb)       // [N, 256] bf16
{
    __shared__ unsigned short Ls[64 * ERS]; // 33792 B; staging uses front 17 KB

    const int t    = threadIdx.x;
    const int w    = t >> 6;                // wave 0..7
    const int lane = t & 63;
    const int m16  = lane & 15;
    const int q    = lane >> 4;             // quad 0..3
    const int nb   = blockIdx.x * 64;
    const int h    = w >> 2;                // 0=U, 1=V
    const int cbase = (w & 3) * 32;         // col slice within half

    // ---- stage x[64][128] -> bf16 LDS, coalesced (2048 float4 / 512 thr) ----
#pragma unroll
    for (int i = 0; i < 4; ++i) {
        const int s   = t + i * 512;        // slot of 4 floats, 0..2047
        const int row = s >> 5;
        const int c4  = s & 31;
        const int gr  = nb + row;
        float4 a = make_float4(0.f, 0.f, 0.f, 0.f);
        if (gr < N_NODES) a = *(const float4*)(x + (size_t)gr * D + c4 * 4);
        const unsigned p0 = (f2bf_u(a.y) << 16) | f2bf_u(a.x);
        const unsigned p1 = (f2bf_u(a.w) << 16) | f2bf_u(a.z);
        *(uint2*)&Ls[row * XRS + c4 * 4] = make_uint2(p0, p1);
    }
    __syncthreads();

    f4 acc[4][2];                           // [node tile rt][col tile ct]
#pragma unroll
    for (int i = 0; i < 4; ++i)
#pragma unroll
        for (int j = 0; j < 2; ++j) acc[i][j] = (f4){0.f, 0.f, 0.f, 0.f};

    int arow[4];
#pragma unroll
    for (int rt = 0; rt < 4; ++rt) arow[rt] = (rt * 16 + m16) * XRS;

#pragma unroll
    for (int ks = 0; ks < 4; ++ks) {
        const int kcol = ks * 32 + q * 8;
        short8 xf[4], wfr[2];
#pragma unroll
        for (int rt = 0; rt < 4; ++rt)
            xf[rt] = *(const short8*)&Ls[arow[rt] + kcol];
        const unsigned short* wfb =
            Wf + ((size_t)(((h * 4 + ks) * 4 + q) * 128 + cbase + m16)) * 8;
#pragma unroll
        for (int ct = 0; ct < 2; ++ct)
            wfr[ct] = *(const short8*)(wfb + (size_t)ct * 16 * 8);
        // A = Wf (W1^T), B = x  ->  D[m=j][n=node]
#pragma unroll
        for (int rt = 0; rt < 4; ++rt)
#pragma unroll
            for (int ct = 0; ct < 2; ++ct)
                acc[rt][ct] = __builtin_amdgcn_mfma_f32_16x16x32_bf16(
                    wfr[ct], xf[rt], acc[rt][ct], 0, 0, 0);
    }

    // b1 folds into the U half only; per lane 4 consecutive j -> float4
    float4 badd[2];
#pragma unroll
    for (int ct = 0; ct < 2; ++ct)
        badd[ct] = (h == 0) ? *(const float4*)(b1 + cbase + ct * 16 + q * 4)
                            : make_float4(0.f, 0.f, 0.f, 0.f);

    __syncthreads();   // all x-frag reads done before we overwrite Ls

    // scatter C-frags into LDS row-major: one b64 per (rt,ct)
#pragma unroll
    for (int rt = 0; rt < 4; ++rt)
#pragma unroll
        for (int ct = 0; ct < 2; ++ct) {
            const int node = rt * 16 + m16;                 // local row
            const int j    = h * 128 + cbase + ct * 16 + q * 4;
            const unsigned p0 =
                (f2bf_u(acc[rt][ct][1] + badd[ct].y) << 16) |
                 f2bf_u(acc[rt][ct][0] + badd[ct].x);
            const unsigned p1 =
                (f2bf_u(acc[rt][ct][3] + badd[ct].w) << 16) |
                 f2bf_u(acc[rt][ct][2] + badd[ct].z);
            *(uint2*)&Ls[node * ERS + j] = make_uint2(p0, p1);
        }
    __syncthreads();

    // coalesced store: thread t -> row t>>3, 32-col chunk (t&7)*32 (64 B)
    const int r  = t >> 3;
    const int c0 = (t & 7) * 32;
    const int grow = nb + r;
    if (grow < N_NODES) {
        const uint4* s = (const uint4*)&Ls[r * ERS + c0];
        uint4* d = (uint4*)(UVb + (size_t)grow * 256 + c0);
#pragma unroll
        for (int i = 0; i < 4; ++i) d[i] = s[i];
    }
}

// ---------------------------------------------------------------------------
// Phase 2 (round-4 version — measured at/near gather roofline):
// out[e] = relu(U[src]+V[tar]) . W2 + b2, UV in bf16.
// Block = 256 thr, 512 edges. Indices staged coalesced into LDS once.
// Each 16-lane group: 4 edges/iter, 8 independent 16-B gathers, 8 iters,
// unroll 2 -> up to 16 gathers in flight. float4 output stores.
// ---------------------------------------------------------------------------
__global__ __launch_bounds__(256) void edge_score_bf(
    const unsigned short* __restrict__ UVb,
    const int* __restrict__ pos,            // [2, E_POS]
    const int* __restrict__ neg,            // [2, E_NEG]
    const float* __restrict__ W2,           // [128]
    const float* __restrict__ b2,           // [1]
    float* __restrict__ out)                // [E_TOT]
{
    __shared__ int sidx[512], tidx[512];

    const int t   = threadIdx.x;
    const int bid = blockIdx.x;
    const int e0  = bid * 512;                       // global edge base
    const int* eidx = (bid < 512) ? pos : neg;       // E_POS = 512*512
    const int lb    = (bid < 512) ? e0 : e0 - E_POS;

    {
        const int2 sp = *(const int2*)(eidx + lb + 2 * t);
        const int2 tp = *(const int2*)(eidx + E_POS + lb + 2 * t);
        *(int2*)&sidx[2 * t] = sp;
        *(int2*)&tidx[2 * t] = tp;
    }
    __syncthreads();

    const int g   = t >> 4;
    const int l16 = t & 15;
    const float4 wa = *(const float4*)(W2 + l16 * 8);
    const float4 wb = *(const float4*)(W2 + l16 * 8 + 4);
    const float bb = b2[0];

#define BF_LO(uv) __uint_as_float((uv) << 16)
#define BF_HI(uv) __uint_as_float((uv) & 0xffff0000u)
#define ACC8(P, U, V)                                                   \
    P = fmaf(fmaxf(BF_LO(U.x) + BF_LO(V.x), 0.f), wa.x, P);             \
    P = fmaf(fmaxf(BF_HI(U.x) + BF_HI(V.x), 0.f), wa.y, P);             \
    P = fmaf(fmaxf(BF_LO(U.y) + BF_LO(V.y), 0.f), wa.z, P);             \
    P = fmaf(fmaxf(BF_HI(U.y) + BF_HI(V.y), 0.f), wa.w, P);             \
    P = fmaf(fmaxf(BF_LO(U.z) + BF_LO(V.z), 0.f), wb.x, P);             \
    P = fmaf(fmaxf(BF_HI(U.z) + BF_HI(V.z), 0.f), wb.y, P);             \
    P = fmaf(fmaxf(BF_LO(U.w) + BF_LO(V.w), 0.f), wb.z, P);             \
    P = fmaf(fmaxf(BF_HI(U.w) + BF_HI(V.w), 0.f), wb.w, P);

#pragma unroll 2
    for (int k = 0; k < 8; ++k) {
        const int el = k * 64 + g * 4;      // 4 consecutive local edges
        const int4 ss = *(const int4*)&sidx[el];
        const int4 tt = *(const int4*)&tidx[el];
        const uint4 U0 = *(const uint4*)(UVb + (size_t)ss.x * 256 + l16 * 8);
        const uint4 U1 = *(const uint4*)(UVb + (size_t)ss.y * 256 + l16 * 8);
        const uint4 U2 = *(const uint4*)(UVb + (size_t)ss.z * 256 + l16 * 8);
        const uint4 U3 = *(const uint4*)(UVb + (size_t)ss.w * 256 + l16 * 8);
        const uint4 V0 = *(const uint4*)(UVb + (size_t)tt.x * 256 + 128 + l16 * 8);
        const uint4 V1 = *(const uint4*)(UVb + (size_t)tt.y * 256 + 128 + l16 * 8);
        const uint4 V2 = *(const uint4*)(UVb + (size_t)tt.z * 256 + 128 + l16 * 8);
        const uint4 V3 = *(const uint4*)(UVb + (size_t)tt.w * 256 + 128 + l16 * 8);

        float p0 = 0.f, p1 = 0.f, p2 = 0.f, p3 = 0.f;
        ACC8(p0, U0, V0)
        ACC8(p1, U1, V1)
        ACC8(p2, U2, V2)
        ACC8(p3, U3, V3)

#pragma unroll
        for (int off = 8; off; off >>= 1) {
            p0 += __shfl_xor(p0, off, 64);
            p1 += __shfl_xor(p1, off, 64);
            p2 += __shfl_xor(p2, off, 64);
            p3 += __shfl_xor(p3, off, 64);
        }

        if (l16 == 0)
            *(float4*)(out + e0 + el) =
                make_float4(p0 + bb, p1 + bb, p2 + bb, p3 + bb);
    }
#undef ACC8
#undef BF_LO
#undef BF_HI
}

// ---------------------------------------------------------------------------
// Fallback (ws too small): one wave per edge, direct fp32 compute.
// ---------------------------------------------------------------------------
__global__ __launch_bounds__(64) void edge_naive(
    const float* __restrict__ x,
    const int* __restrict__ pos, const int* __restrict__ neg,
    const float* __restrict__ W1, const float* __restrict__ b1,
    const float* __restrict__ W2, const float* __restrict__ b2,
    float* __restrict__ out)
{
    const int lane = threadIdx.x;
    for (int e = blockIdx.x; e < E_TOT; e += gridDim.x) {
        int src, tar;
        if (e < E_POS) { src = pos[e]; tar = pos[E_POS + e]; }
        else { int e2 = e - E_POS; src = neg[e2]; tar = neg[E_NEG + e2]; }
        const float* xsrc = x + (size_t)src * D;
        const float* xtar = x + (size_t)tar * D;
        int j = lane * 2;
        float h0 = b1[j], h1 = b1[j + 1];
        for (int k = 0; k < D; ++k) {
            float a = xsrc[k], b = xtar[k];
            h0 = fmaf(a, W1[(size_t)k * D + j],       h0);
            h0 = fmaf(b, W1[(size_t)(k + D) * D + j], h0);
            h1 = fmaf(a, W1[(size_t)k * D + j + 1],       h1);
            h1 = fmaf(b, W1[(size_t)(k + D) * D + j + 1], h1);
        }
        float p = fmaf(fmaxf(h0, 0.f), W2[j], fmaxf(h1, 0.f) * W2[j + 1]);
#pragma unroll
        for (int off = 32; off > 0; off >>= 1) p += __shfl_xor(p, off, 64);
        if (lane == 0) out[e] = p + b2[0];
    }
}

extern "C" void kernel_launch(void* const* d_in, const int* in_sizes, int n_in,
                              void* d_out, int out_size, void* d_ws, size_t ws_size,
                              hipStream_t stream) {
    const float* x   = (const float*)d_in[0];
    const int*   pos = (const int*)d_in[1];
    const int*   neg = (const int*)d_in[2];
    const float* W1  = (const float*)d_in[3];
    const float* b1  = (const float*)d_in[4];
    const float* W2  = (const float*)d_in[5];
    const float* b2  = (const float*)d_in[6];
    float* out = (float*)d_out;

    const size_t uv_bytes = (size_t)N_NODES * 256 * sizeof(unsigned short);
    const size_t wf_bytes = 32768 * sizeof(unsigned short);
    if (ws_size >= uv_bytes + wf_bytes) {
        unsigned short* UVb = (unsigned short*)d_ws;
        unsigned short* Wfr = (unsigned short*)((char*)d_ws + uv_bytes);
        pack_w1<<<16, 256, 0, stream>>>(W1, Wfr);
        node_gemm_mfma<<<(N_NODES + 63) / 64, 512, 0, stream>>>(x, Wfr, b1, UVb);
        edge_score_bf<<<E_TOT / 512, 256, 0, stream>>>(UVb, pos, neg, W2, b2, out);
    } else {
        edge_naive<<<8192, 64, 0, stream>>>(x, pos, neg, W1, b1, W2, b2, out);
    }
}

// Round 7
// 152.279 us; speedup vs baseline: 1.0840x; 1.0235x over previous
//
#include <hip/hip_runtime.h>

#define N_NODES 100000
#define D 128
#define E_POS 262144
#define E_NEG 262144
#define E_TOT (E_POS + E_NEG)
#define NT 1563           // ceil(N_NODES/64) node tiles

typedef __attribute__((ext_vector_type(8))) short short8;  // 8 bf16 (4 VGPRs)
typedef __attribute__((ext_vector_type(4))) float f4;      // MFMA C/D frag

__device__ __forceinline__ unsigned f2bf_u(float f) {
    // round-to-nearest-even fp32 -> bf16 (inputs finite; no NaN path)
    unsigned u = __float_as_uint(f);
    return (u + 0x7fffu + ((u >> 16) & 1u)) >> 16;
}

// ---------------------------------------------------------------------------
// Prep: pack W1 (fp32 [256,128]) into bf16 MFMA fragment layout:
//   Wf[((h*4+ks)*4+q)*128 + c][j] = bf16( W1[h*128 + ks*32 + q*8 + j][c] )
// Serves as the A-operand (W1^T) in the swapped-orientation MFMA.
// 64 KB total (L2-resident).
// ---------------------------------------------------------------------------
__global__ __launch_bounds__(256) void pack_w1(
    const float* __restrict__ W1, unsigned short* __restrict__ Wf)
{
    const int tid = blockIdx.x * 256 + threadIdx.x;   // 4096 groups
    if (tid >= 4096) return;
    const int h  = tid >> 11;
    const int ks = (tid >> 9) & 3;
    const int q  = (tid >> 7) & 3;
    const int c  = tid & 127;
    const int kb = h * 128 + ks * 32 + q * 8;
    const float* src = W1 + (size_t)kb * D + c;
    unsigned short tmp[8];
#pragma unroll
    for (int j = 0; j < 8; ++j) tmp[j] = (unsigned short)f2bf_u(src[(size_t)j * D]);
    *(uint4*)(Wf + (size_t)tid * 8) = *(const uint4*)tmp;
}

// ---------------------------------------------------------------------------
// Phase 1 (bf16 MFMA, swapped orientation, persistent + pipelined):
//   UVb[n][j<128] = sum_k x[n][k]*W1[k][j] + b1[j]      (U)
//   UVb[n][128+j] = sum_k x[n][k]*W1[128+k][j]          (V)
// 512 thr = 8 waves; 64 nodes x 256 cols per tile; wave w -> h=w>>2 half,
// 32-col slice (w&3)*32. D[m=j][n=node] = Wf(A) * x(B): per lane the C frag
// is 4 CONSECUTIVE j for one node -> epilogue ds_write_b64.
// Persistent: each block loops tiles bid, bid+grid; x loads for the NEXT
// tile issue right after bar1, overlapping this tile's MFMA + epilogue.
// All 8 Wf frags held in VGPRs for the whole kernel (L2-hot, tile-invariant).
// __launch_bounds__(512,4): 128-VGPR budget -> ILP; LDS 51.2KB -> 3 blk/CU.
// Two barriers/tile: stage-write->compute-read and epi-write->epi-read
// (separate LDS regions make the third barrier redundant; see comments).
// MFMA layouts (measured, m89/m91): A[m=lane&15][k=q*8+j],
// B[k=q*8+j][n=lane&15], C: col(n)=lane&15, row(m)=q*4+reg.
// ---------------------------------------------------------------------------
#define XRS 136   // staging row stride in shorts (272 B: 16-B aligned)
#define ERS 264   // epilogue row stride in shorts (528 B: 16-B aligned)
#define GRID1 783 // gemm grid: ~3 blocks/CU-generation, 2 tiles/block max

__global__ __launch_bounds__(512, 4) void node_gemm_mfma(
    const float* __restrict__ x,            // [N, 128]
    const unsigned short* __restrict__ Wf,  // packed W1^T frags
    const float* __restrict__ b1,           // [128]
    unsigned short* __restrict__ UVb)       // [N, 256] bf16
{
    __shared__ unsigned short Ls[64 * XRS + 64 * ERS];  // 51200 B
    unsigned short* const Es = Ls + 64 * XRS;           // epilogue region

    const int t    = threadIdx.x;
    const int w    = t >> 6;                // wave 0..7
    const int lane = t & 63;
    const int m16  = lane & 15;
    const int q    = lane >> 4;             // quad 0..3
    const int h    = w >> 2;                // 0=U, 1=V
    const int cbase = (w & 3) * 32;         // col slice within half

    // ---- tile-invariant: Wf frags (8 x short8 = 32 VGPRs) + b1 ----
    short8 wfr[4][2];
#pragma unroll
    for (int ks = 0; ks < 4; ++ks) {
        const unsigned short* wfb =
            Wf + ((size_t)(((h * 4 + ks) * 4 + q) * 128 + cbase + m16)) * 8;
        wfr[ks][0] = *(const short8*)wfb;
        wfr[ks][1] = *(const short8*)(wfb + 16 * 8);
    }
    float4 badd[2];
#pragma unroll
    for (int ct = 0; ct < 2; ++ct)
        badd[ct] = (h == 0) ? *(const float4*)(b1 + cbase + ct * 16 + q * 4)
                            : make_float4(0.f, 0.f, 0.f, 0.f);

    // ---- prologue: issue x loads for first tile ----
    int tile = blockIdx.x;
    float4 xr[4];
#pragma unroll
    for (int i = 0; i < 4; ++i) {
        const int s  = t + i * 512;
        int gr = tile * 64 + (s >> 5);
        if (gr >= N_NODES) gr = N_NODES - 1;
        xr[i] = *(const float4*)(x + (size_t)gr * D + (s & 31) * 4);
    }

    for (; tile < NT; tile += GRID1) {
        const int nb = tile * 64;

        // ---- stage x regs -> bf16 LDS ----
#pragma unroll
        for (int i = 0; i < 4; ++i) {
            const int s = t + i * 512;
            const unsigned p0 = (f2bf_u(xr[i].y) << 16) | f2bf_u(xr[i].x);
            const unsigned p1 = (f2bf_u(xr[i].w) << 16) | f2bf_u(xr[i].z);
            *(uint2*)&Ls[(s >> 5) * XRS + (s & 31) * 4] = make_uint2(p0, p1);
        }
        __syncthreads();   // bar1: stage visible; also guards prev epi reads

        // ---- prefetch next tile's x while computing this one ----
        const int ntile = tile + GRID1;
        float4 xr2[4];
        if (ntile < NT) {
#pragma unroll
            for (int i = 0; i < 4; ++i) {
                const int s  = t + i * 512;
                int gr = ntile * 64 + (s >> 5);
                if (gr >= N_NODES) gr = N_NODES - 1;
                xr2[i] = *(const float4*)(x + (size_t)gr * D + (s & 31) * 4);
            }
        } else {
#pragma unroll
            for (int i = 0; i < 4; ++i) xr2[i] = xr[i];
        }

        // ---- MFMA: A=Wf(W1^T), B=x -> D[m=j][n=node] ----
        f4 acc[4][2];
#pragma unroll
        for (int i = 0; i < 4; ++i)
#pragma unroll
            for (int j = 0; j < 2; ++j) acc[i][j] = (f4){0.f, 0.f, 0.f, 0.f};

#pragma unroll
        for (int ks = 0; ks < 4; ++ks) {
            const int kcol = ks * 32 + q * 8;
            short8 xf[4];
#pragma unroll
            for (int rt = 0; rt < 4; ++rt)
                xf[rt] = *(const short8*)&Ls[(rt * 16 + m16) * XRS + kcol];
#pragma unroll
            for (int rt = 0; rt < 4; ++rt)
#pragma unroll
                for (int ct = 0; ct < 2; ++ct)
                    acc[rt][ct] = __builtin_amdgcn_mfma_f32_16x16x32_bf16(
                        wfr[ks][ct], xf[rt], acc[rt][ct], 0, 0, 0);
        }

        // ---- epilogue: C-frags -> Es row-major (b64 per frag) ----
        // (no barrier needed before this: Es != stage region; prev-iter Es
        //  reads completed before this iter's bar1)
#pragma unroll
        for (int rt = 0; rt < 4; ++rt)
#pragma unroll
            for (int ct = 0; ct < 2; ++ct) {
                const int node = rt * 16 + m16;
                const int j    = h * 128 + cbase + ct * 16 + q * 4;
                const unsigned p0 =
                    (f2bf_u(acc[rt][ct][1] + badd[ct].y) << 16) |
                     f2bf_u(acc[rt][ct][0] + badd[ct].x);
                const unsigned p1 =
                    (f2bf_u(acc[rt][ct][3] + badd[ct].w) << 16) |
                     f2bf_u(acc[rt][ct][2] + badd[ct].z);
                *(uint2*)&Es[node * ERS + j] = make_uint2(p0, p1);
            }
        __syncthreads();   // bar2: epi visible (also: all stage reads done,
                           // so next iter may rewrite stage after loop)

        // ---- coalesced store: row t>>3, 32-col chunk (t&7)*32 (64 B) ----
        const int r    = t >> 3;
        const int c0   = (t & 7) * 32;
        const int grow = nb + r;
        if (grow < N_NODES) {
            const uint4* s = (const uint4*)&Es[r * ERS + c0];
            uint4* d = (uint4*)(UVb + (size_t)grow * 256 + c0);
#pragma unroll
            for (int i = 0; i < 4; ++i) d[i] = s[i];
        }

#pragma unroll
        for (int i = 0; i < 4; ++i) xr[i] = xr2[i];
    }
}

// ---------------------------------------------------------------------------
// Phase 2 (measured at gather roofline ~6.7 TB/s effective — unchanged):
// out[e] = relu(U[src]+V[tar]) . W2 + b2, UV in bf16.
// Block = 256 thr, 512 edges. Indices staged coalesced into LDS once.
// Each 16-lane group: 4 edges/iter, 8 independent 16-B gathers, 8 iters,
// unroll 2 -> up to 16 gathers in flight. float4 output stores.
// ---------------------------------------------------------------------------
__global__ __launch_bounds__(256) void edge_score_bf(
    const unsigned short* __restrict__ UVb,
    const int* __restrict__ pos,            // [2, E_POS]
    const int* __restrict__ neg,            // [2, E_NEG]
    const float* __restrict__ W2,           // [128]
    const float* __restrict__ b2,           // [1]
    float* __restrict__ out)                // [E_TOT]
{
    __shared__ int sidx[512], tidx[512];

    const int t   = threadIdx.x;
    const int bid = blockIdx.x;
    const int e0  = bid * 512;                       // global edge base
    const int* eidx = (bid < 512) ? pos : neg;       // E_POS = 512*512
    const int lb    = (bid < 512) ? e0 : e0 - E_POS;

    {
        const int2 sp = *(const int2*)(eidx + lb + 2 * t);
        const int2 tp = *(const int2*)(eidx + E_POS + lb + 2 * t);
        *(int2*)&sidx[2 * t] = sp;
        *(int2*)&tidx[2 * t] = tp;
    }
    __syncthreads();

    const int g   = t >> 4;
    const int l16 = t & 15;
    const float4 wa = *(const float4*)(W2 + l16 * 8);
    const float4 wb = *(const float4*)(W2 + l16 * 8 + 4);
    const float bb = b2[0];

#define BF_LO(uv) __uint_as_float((uv) << 16)
#define BF_HI(uv) __uint_as_float((uv) & 0xffff0000u)
#define ACC8(P, U, V)                                                   \
    P = fmaf(fmaxf(BF_LO(U.x) + BF_LO(V.x), 0.f), wa.x, P);             \
    P = fmaf(fmaxf(BF_HI(U.x) + BF_HI(V.x), 0.f), wa.y, P);             \
    P = fmaf(fmaxf(BF_LO(U.y) + BF_LO(V.y), 0.f), wa.z, P);             \
    P = fmaf(fmaxf(BF_HI(U.y) + BF_HI(V.y), 0.f), wa.w, P);             \
    P = fmaf(fmaxf(BF_LO(U.z) + BF_LO(V.z), 0.f), wb.x, P);             \
    P = fmaf(fmaxf(BF_HI(U.z) + BF_HI(V.z), 0.f), wb.y, P);             \
    P = fmaf(fmaxf(BF_LO(U.w) + BF_LO(V.w), 0.f), wb.z, P);             \
    P = fmaf(fmaxf(BF_HI(U.w) + BF_HI(V.w), 0.f), wb.w, P);

#pragma unroll 2
    for (int k = 0; k < 8; ++k) {
        const int el = k * 64 + g * 4;      // 4 consecutive local edges
        const int4 ss = *(const int4*)&sidx[el];
        const int4 tt = *(const int4*)&tidx[el];
        const uint4 U0 = *(const uint4*)(UVb + (size_t)ss.x * 256 + l16 * 8);
        const uint4 U1 = *(const uint4*)(UVb + (size_t)ss.y * 256 + l16 * 8);
        const uint4 U2 = *(const uint4*)(UVb + (size_t)ss.z * 256 + l16 * 8);
        const uint4 U3 = *(const uint4*)(UVb + (size_t)ss.w * 256 + l16 * 8);
        const uint4 V0 = *(const uint4*)(UVb + (size_t)tt.x * 256 + 128 + l16 * 8);
        const uint4 V1 = *(const uint4*)(UVb + (size_t)tt.y * 256 + 128 + l16 * 8);
        const uint4 V2 = *(const uint4*)(UVb + (size_t)tt.z * 256 + 128 + l16 * 8);
        const uint4 V3 = *(const uint4*)(UVb + (size_t)tt.w * 256 + 128 + l16 * 8);

        float p0 = 0.f, p1 = 0.f, p2 = 0.f, p3 = 0.f;
        ACC8(p0, U0, V0)
        ACC8(p1, U1, V1)
        ACC8(p2, U2, V2)
        ACC8(p3, U3, V3)

#pragma unroll
        for (int off = 8; off; off >>= 1) {
            p0 += __shfl_xor(p0, off, 64);
            p1 += __shfl_xor(p1, off, 64);
            p2 += __shfl_xor(p2, off, 64);
            p3 += __shfl_xor(p3, off, 64);
        }

        if (l16 == 0)
            *(float4*)(out + e0 + el) =
                make_float4(p0 + bb, p1 + bb, p2 + bb, p3 + bb);
    }
#undef ACC8
#undef BF_LO
#undef BF_HI
}

// ---------------------------------------------------------------------------
// Fallback (ws too small): one wave per edge, direct fp32 compute.
// ---------------------------------------------------------------------------
__global__ __launch_bounds__(64) void edge_naive(
    const float* __restrict__ x,
    const int* __restrict__ pos, const int* __restrict__ neg,
    const float* __restrict__ W1, const float* __restrict__ b1,
    const float* __restrict__ W2, const float* __restrict__ b2,
    float* __restrict__ out)
{
    const int lane = threadIdx.x;
    for (int e = blockIdx.x; e < E_TOT; e += gridDim.x) {
        int src, tar;
        if (e < E_POS) { src = pos[e]; tar = pos[E_POS + e]; }
        else { int e2 = e - E_POS; src = neg[e2]; tar = neg[E_NEG + e2]; }
        const float* xsrc = x + (size_t)src * D;
        const float* xtar = x + (size_t)tar * D;
        int j = lane * 2;
        float h0 = b1[j], h1 = b1[j + 1];
        for (int k = 0; k < D; ++k) {
            float a = xsrc[k], b = xtar[k];
            h0 = fmaf(a, W1[(size_t)k * D + j],       h0);
            h0 = fmaf(b, W1[(size_t)(k + D) * D + j], h0);
            h1 = fmaf(a, W1[(size_t)k * D + j + 1],       h1);
            h1 = fmaf(b, W1[(size_t)(k + D) * D + j + 1], h1);
        }
        float p = fmaf(fmaxf(h0, 0.f), W2[j], fmaxf(h1, 0.f) * W2[j + 1]);
#pragma unroll
        for (int off = 32; off > 0; off >>= 1) p += __shfl_xor(p, off, 64);
        if (lane == 0) out[e] = p + b2[0];
    }
}

extern "C" void kernel_launch(void* const* d_in, const int* in_sizes, int n_in,
                              void* d_out, int out_size, void* d_ws, size_t ws_size,
                              hipStream_t stream) {
    const float* x   = (const float*)d_in[0];
    const int*   pos = (const int*)d_in[1];
    const int*   neg = (const int*)d_in[2];
    const float* W1  = (const float*)d_in[3];
    const float* b1  = (const float*)d_in[4];
    const float* W2  = (const float*)d_in[5];
    const float* b2  = (const float*)d_in[6];
    float* out = (float*)d_out;

    const size_t uv_bytes = (size_t)N_NODES * 256 * sizeof(unsigned short);
    const size_t wf_bytes = 32768 * sizeof(unsigned short);
    if (ws_size >= uv_bytes + wf_bytes) {
        unsigned short* UVb = (unsigned short*)d_ws;
        unsigned short* Wfr = (unsigned short*)((char*)d_ws + uv_bytes);
        pack_w1<<<16, 256, 0, stream>>>(W1, Wfr);
        node_gemm_mfma<<<GRID1, 512, 0, stream>>>(x, Wfr, b1, UVb);
        edge_score_bf<<<E_TOT / 512, 256, 0, stream>>>(UVb, pos, neg, W2, b2, out);
    } else {
        edge_naive<<<8192, 64, 0, stream>>>(x, pos, neg, W1, b1, W2, b2, out);
    }
}